// Round 19
// baseline (108.136 us; speedup 1.0000x reference)
//
#include <hip/hip_runtime.h>

#define B_ 8
#define T_ 256
#define U_ 64
#define U1_ 65
#define V_ 512
#define NDIAGP_ 336   // padded diagonal count (GLDS over-read stays in-bounds)
#define NTP_ 4        // t-rows per producer block
#define NPROD_ (B_ * T_ / NTP_)   // 512 producer blocks
#define NTG_ (T_ / NTP_)          // 64 flags per batch
#define CH_ 64        // diagonals per chunk
#define MAGIC_ 0x5F3C9D71

#define LOG2E_ 1.4426950408889634f
#define LN2_   0.6931471805599453f

#if __has_builtin(__builtin_amdgcn_exp2f)
#define EXP2(x) __builtin_amdgcn_exp2f(x)
#else
#define EXP2(x) exp2f(x)
#endif

// ---------------------------------------------------------------------------
// DPP helpers
// ---------------------------------------------------------------------------
template <int CTRL, int RM>
__device__ __forceinline__ float dppadd(float x) {
    return x + __int_as_float(__builtin_amdgcn_update_dpp(
        0, __float_as_int(x), CTRL, RM, 0xf, true));
}
__device__ __forceinline__ float wave_sum64(float x) {
    x = dppadd<0x111, 0xf>(x);  // row_shr:1
    x = dppadd<0x112, 0xf>(x);  // row_shr:2
    x = dppadd<0x114, 0xf>(x);  // row_shr:4
    x = dppadd<0x118, 0xf>(x);  // row_shr:8
    x = dppadd<0x142, 0xa>(x);  // row_bcast:15 -> rows 1,3
    x = dppadd<0x143, 0xc>(x);  // row_bcast:31 -> rows 2,3
    return x;                    // lane 63 holds the full sum
}
__device__ __forceinline__ float wshr1(float x) {
    return __int_as_float(__builtin_amdgcn_update_dpp(
        0, __float_as_int(x), 0x138, 0xf, 0xf, true));
}
template <int CTRL>
__device__ __forceinline__ float dppmax(float x) {
    return fmaxf(x, __int_as_float(__builtin_amdgcn_update_dpp(
        0, __float_as_int(x), CTRL, 0xf, 0xf, false)));
}
__device__ __forceinline__ float wave_max64(float x) {
    x = dppmax<0x111>(x);
    x = dppmax<0x112>(x);
    x = dppmax<0x114>(x);
    x = dppmax<0x118>(x);
    x = dppmax<0x142>(x);
    x = dppmax<0x143>(x);
    return __int_as_float(__builtin_amdgcn_readlane(__float_as_int(x), 63));
}

// Spin until flags[min(lane,lim)] == MAGIC for all lanes (acquire, agent).
__device__ __forceinline__ void wait_flags(const int* fb, int lim, int lane) {
    const int idx = lane < lim ? lane : lim;
    for (;;) {
        int v = __hip_atomic_load(fb + idx, __ATOMIC_ACQUIRE,
                                  __HIP_MEMORY_SCOPE_AGENT);
        if (__all(v == MAGIC_)) return;
        __builtin_amdgcn_s_sleep(8);
    }
}

// ---------------------------------------------------------------------------
// consumer pipeline macros (R18 k_alpha, unchanged math)
// ---------------------------------------------------------------------------
#define GLDS(c_) do {                                                           \
    if (wave > 0) {                                                             \
        const float* gbl = BLb + (size_t)(c_) * CH_ * U1_;                      \
        const float* gem = EMb + (size_t)(c_) * CH_ * U_;                       \
        float* lbl_ = sRBL[(c_) & 1];                                           \
        float* lem_ = sREM[(c_) & 1];                                           \
        for (int i = wave - 1; i < 17; i += 7)                                  \
            __builtin_amdgcn_global_load_lds(                                   \
                (const __attribute__((address_space(1))) void*)(gbl + i * 256 + lane * 4), \
                (__attribute__((address_space(3))) void*)(lbl_ + i * 256), 16, 0, 0);      \
        for (int i = wave - 1; i < 16; i += 7)                                  \
            __builtin_amdgcn_global_load_lds(                                   \
                (const __attribute__((address_space(1))) void*)(gem + i * 256 + lane * 4), \
                (__attribute__((address_space(3))) void*)(lem_ + i * 256), 16, 0, 0);      \
    }                                                                           \
} while (0)

#define CONV(c_) do {                                                           \
    if (wave > 0) {                                                             \
        const float* rbl = sRBL[(c_) & 1];                                      \
        const float* rem = sREM[(c_) & 1];                                      \
        float4* pv_ = sPV[(c_) & 1];                                            \
        float*  pc_ = sPC[(c_) & 1];                                            \
        _Pragma("unroll 3")                                                     \
        for (int i = wave - 1; i < CH_; i += 7) {                               \
            const float bl = rbl[i * U1_ + lane + 1];                           \
            const float em = rem[i * U_ + lane];                                \
            const float pc = ((c_) == 4) ? rbl[i * U1_ + i + 1]                 \
                                         : rbl[i * U1_];                        \
            float vb = fminf(bl - pc, 126.0f);                                  \
            float ve = fminf(em - pc, 126.0f);                                  \
            if ((c_) == 0 && lane == i) vb = -200.0f;                           \
            if ((c_) == 4 && lane <= i) { vb = -200.0f; ve = -200.0f; }         \
            ((float2*)&pv_[(i >> 1) * 64 + lane])[i & 1] =                      \
                make_float2(EXP2(vb), EXP2(ve));                                \
            if (lane == 0) pc_[i] = pc;                                         \
        }                                                                       \
    }                                                                           \
} while (0)

#define LOADG(PV, PCQ, g_) do {                                                 \
    _Pragma("unroll")                                                           \
    for (int k = 0; k < 4; ++k)                                                 \
        PV[k] = pvb[(4 * (g_) + k) * 64 + lane];                                \
    PCQ[0] = pcb4[2 * (g_)];                                                    \
    PCQ[1] = pcb4[2 * (g_) + 1];                                                \
} while (0)

#define PCSEL(PCQ, j_) ((j_) < 4 ? ((j_) == 0 ? PCQ[0].x : (j_) == 1 ? PCQ[0].y \
                                  : (j_) == 2 ? PCQ[0].z : PCQ[0].w)            \
                                 : ((j_) == 4 ? PCQ[1].x : (j_) == 5 ? PCQ[1].y \
                                  : (j_) == 6 ? PCQ[1].z : PCQ[1].w))

#define COMPG(PV, PCQ, g_) do {                                                 \
    _Pragma("unroll")                                                           \
    for (int j = 0; j < 8; ++j) {                                               \
        const int d = d0 + 8 * (g_) + j + 1;                                    \
        const float pbv = (j & 1) ? PV[j >> 1].z : PV[j >> 1].x;                \
        const float pev = (j & 1) ? PV[j >> 1].w : PV[j >> 1].y;                \
        const float pcj = PCSEL(PCQ, j);                                        \
        float sr = wshr1(r);                                                    \
        sr = lane0 ? r0 : sr;                                                   \
        r = fmaf(sr, pev, r * pbv);                                             \
        const bool cap = (d == cap_d);                                          \
        savedV = cap ? (tlpos ? r : r0) : savedV;                               \
        savedC = cap ? (tlpos ? Rc + pcj : Rc) : savedC;                        \
        Rc += pcj;                                                              \
    }                                                                           \
    {                                                                           \
        float m = wave_max64(r);                                                \
        int mb = __float_as_int(m);                                             \
        int e = (mb >> 23) - 127;                                               \
        e = (mb >= 0x00800000) ? e : 0;                                         \
        float sc = __int_as_float((127 - e) << 23);                             \
        r *= sc;  r0 *= sc;  Rc += (float)e;                                    \
    }                                                                           \
} while (0)

#define CHUNK_BODY(c_) do {                                                     \
    const float4* pvb  = sPV[(c_) & 1];                                         \
    const float4* pcb4 = (const float4*)sPC[(c_) & 1];                          \
    const int d0 = CH_ * (c_);                                                  \
    float4 pvA[4], pvB[4];                                                      \
    float4 pcA[2], pcB[2];                                                      \
    LOADG(pvA, pcA, 0);                                                         \
    for (int g = 0; g < 8; g += 2) {                                            \
        LOADG(pvB, pcB, g + 1);                                                 \
        COMPG(pvA, pcA, g);                                                     \
        if (g + 2 < 8) LOADG(pvA, pcA, g + 2);                                  \
        COMPG(pvB, pcB, g + 1);                                                 \
    }                                                                           \
} while (0)

// ---------------------------------------------------------------------------
// Fused kernel: blocks 0..511 produce BLD/EMD (diag-major log2 logprobs);
// blocks 512..519 run the alpha recursion, flag-synchronized.
// ---------------------------------------------------------------------------
__global__ __launch_bounds__(512) void k_fused(
    const float* __restrict__ enc, const float* __restrict__ dec,
    const int* __restrict__ targets,
    const int* __restrict__ il_, const int* __restrict__ tl_,
    float* __restrict__ BLD, float* __restrict__ EMD,
    int* __restrict__ flags, float* __restrict__ partial,
    int* __restrict__ pflag, float* __restrict__ out)
{
    __shared__ __align__(16) float  sRBL[2][17 * 256];   // raw BL (34 KB)
    __shared__ __align__(16) float  sREM[2][16 * 256];   // raw EM (32 KB)
    __shared__ __align__(16) float4 sPV[2][32 * 64];     // packed pairs (64 KB)
    __shared__ __align__(16) float  sPC[2][CH_];         // refs (512 B)

    const int blk  = blockIdx.x;
    const int wave = threadIdx.x >> 6;
    const int lane = threadIdx.x & 63;

    if (blk < NPROD_) {
        // ========================= producer =========================
        const int b  = blk % B_;              // XCD affinity with consumer b
        const int tg = blk / B_;
        const int t0 = tg * NTP_;

        float4 xe0[NTP_], xe1[NTP_];
        float  er0[NTP_];
        #pragma unroll
        for (int j = 0; j < NTP_; ++j) {
            const float* erow = enc + (size_t)(b * T_ + t0 + j) * V_;
            float4 e0 = *(const float4*)(erow + lane * 4);
            float4 e1 = *(const float4*)(erow + 256 + lane * 4);
            xe0[j].x = __expf(e0.x); xe0[j].y = __expf(e0.y);
            xe0[j].z = __expf(e0.z); xe0[j].w = __expf(e0.w);
            xe1[j].x = __expf(e1.x); xe1[j].y = __expf(e1.y);
            xe1[j].z = __expf(e1.z); xe1[j].w = __expf(e1.w);
            er0[j] = erow[0];
        }

        for (int u = wave; u <= U_; u += 8) {
            const float* drow = dec + (size_t)(b * U1_ + u) * V_;
            float4 d0 = *(const float4*)(drow + lane * 4);
            float4 d1 = *(const float4*)(drow + 256 + lane * 4);
            d0.x = __expf(d0.x); d0.y = __expf(d0.y);
            d0.z = __expf(d0.z); d0.w = __expf(d0.w);
            d1.x = __expf(d1.x); d1.y = __expf(d1.y);
            d1.z = __expf(d1.z); d1.w = __expf(d1.w);

            float s[NTP_];
            #pragma unroll
            for (int j = 0; j < NTP_; ++j) {
                float sA = xe0[j].x * d0.x;
                float sB = xe1[j].x * d1.x;
                sA = fmaf(xe0[j].y, d0.y, sA);  sB = fmaf(xe1[j].y, d1.y, sB);
                sA = fmaf(xe0[j].z, d0.z, sA);  sB = fmaf(xe1[j].z, d1.z, sB);
                sA = fmaf(xe0[j].w, d0.w, sA);  sB = fmaf(xe1[j].w, d1.w, sB);
                s[j] = sA + sB;
            }

            #pragma unroll
            for (int j = 0; j < NTP_; ++j)
                s[j] = wave_sum64(s[j]);

            if (lane == 63) {
                const float d_blank = drow[0];
                int   tgt = 0;
                float d_tgt = 0.0f;
                if (u < U_) { tgt = targets[b * U_ + u]; d_tgt = drow[tgt]; }
                #pragma unroll
                for (int j = 0; j < NTP_; ++j) {
                    const int t  = t0 + j;
                    const int dg = t + u;
                    const float lse2 = log2f(s[j]);
                    BLD[((size_t)b * NDIAGP_ + dg) * U1_ + u] =
                        (er0[j] + d_blank) * LOG2E_ - lse2;
                    if (u < U_) {
                        const float* er = enc + (size_t)(b * T_ + t) * V_;
                        EMD[((size_t)b * NDIAGP_ + dg) * U_ + u] =
                            (er[tgt] + d_tgt) * LOG2E_ - lse2;
                    }
                }
            }
        }
        __syncthreads();                 // all waves' stores issued+drained
        __threadfence();                 // device-scope release of data
        if (threadIdx.x == 0)
            __hip_atomic_store(&flags[b * NTG_ + tg], MAGIC_,
                               __ATOMIC_RELEASE, __HIP_MEMORY_SCOPE_AGENT);
        return;
    }

    // ========================= consumer =========================
    const int b = blk - NPROD_;
    const int* fb = flags + b * NTG_;
    const int il   = il_[b];
    const int tl   = tl_[b];
    const int dstar = il - 1 + tl;
    const float* BLb = BLD + (size_t)b * NDIAGP_ * U1_;
    const float* EMb = EMD + (size_t)b * NDIAGP_ * U_;

    const bool lane0 = (lane == 0);
    const bool tlpos = (tl > 0);
    const int  cap_d = tlpos ? dstar : il;

    float r  = 0.0f;
    float r0 = 1.0f;
    float Rc = 0.0f;
    float savedV = 1.0f, savedC = 0.0f;

    wait_flags(fb, 15, lane);            // chunk 0: t <= 63
    GLDS(0);
    __syncthreads();
    wait_flags(fb, 31, lane);            // chunk 1: t <= 127
    GLDS(1);
    CONV(0);
    __syncthreads();

    for (int c = 0; c < 5; ++c) {
        if (c + 2 <= 4) {
            const int lim = 16 * (c + 2) + 15;
            wait_flags(fb, lim > 63 ? 63 : lim, lane);
            GLDS(c + 2);
        }
        if (c + 1 <= 4) CONV(c + 1);
        if (wave == 0) { CHUNK_BODY(c); }
        __syncthreads();
    }

    if (wave == 0) {
        const float fblank = BLb[(size_t)dstar * U1_ + tl];
        const int sl = tlpos ? (tl - 1) : 0;
        float sv = __int_as_float(
            __builtin_amdgcn_readlane(__float_as_int(savedV), sl));
        float sc = __int_as_float(
            __builtin_amdgcn_readlane(__float_as_int(savedC), 0));
        if (lane == 0) {
            const float term = sc + log2f(sv) + fblank;
            if (b == 0) {
                float sum = term;
                for (int l = 1; l < B_; ++l) {
                    while (__hip_atomic_load(&pflag[l], __ATOMIC_ACQUIRE,
                                             __HIP_MEMORY_SCOPE_AGENT) != MAGIC_)
                        __builtin_amdgcn_s_sleep(8);
                    sum += partial[l];
                }
                out[0] = -sum * (LN2_ / B_);
            } else {
                partial[b] = term;
                __threadfence();
                __hip_atomic_store(&pflag[b], MAGIC_,
                                   __ATOMIC_RELEASE, __HIP_MEMORY_SCOPE_AGENT);
            }
        }
    }
}

extern "C" void kernel_launch(void* const* d_in, const int* in_sizes, int n_in,
                              void* d_out, int out_size, void* d_ws, size_t ws_size,
                              hipStream_t stream)
{
    const float* enc     = (const float*)d_in[0];
    const float* dec     = (const float*)d_in[1];
    const int*   targets = (const int*)d_in[2];
    const int*   il      = (const int*)d_in[3];
    const int*   tl      = (const int*)d_in[4];
    float*       out     = (float*)d_out;

    float* BLD     = (float*)d_ws;                        // B*NDIAGP*U1
    float* EMD     = BLD + (size_t)B_ * NDIAGP_ * U1_;    // B*NDIAGP*U_
    int*   flags   = (int*)(EMD + (size_t)B_ * NDIAGP_ * U_);   // B*NTG_
    float* partial = (float*)(flags + B_ * NTG_);         // B_ floats
    int*   pflag   = (int*)(partial + B_);                // B_ ints

    k_fused<<<NPROD_ + B_, 512, 0, stream>>>(enc, dec, targets, il, tl,
                                             BLD, EMD, flags, partial, pflag, out);
}

// Round 20
// 39.623 us; speedup vs baseline: 2.7292x; 2.7292x over previous
//
#include <hip/hip_runtime.h>

#define B_ 8
#define T_ 256
#define U_ 64
#define U1_ 65
#define V_ 512
#define NDIAGP_ 336   // padded diagonal count
#define NT_ 2         // t-rows per k_logprobs block
#define ND_ 320       // diagonals 0..319 (recursion d = 1..320 reads row d-1)

#define LOG2E_ 1.4426950408889634f
#define LN2_   0.6931471805599453f

#if __has_builtin(__builtin_amdgcn_exp2f)
#define EXP2(x) __builtin_amdgcn_exp2f(x)
#else
#define EXP2(x) exp2f(x)
#endif

// ---------------------------------------------------------------------------
// DPP helpers
// ---------------------------------------------------------------------------
template <int CTRL, int RM>
__device__ __forceinline__ float dppadd(float x) {
    return x + __int_as_float(__builtin_amdgcn_update_dpp(
        0, __float_as_int(x), CTRL, RM, 0xf, true));
}
__device__ __forceinline__ float wave_sum64(float x) {
    x = dppadd<0x111, 0xf>(x);  // row_shr:1
    x = dppadd<0x112, 0xf>(x);  // row_shr:2
    x = dppadd<0x114, 0xf>(x);  // row_shr:4
    x = dppadd<0x118, 0xf>(x);  // row_shr:8
    x = dppadd<0x142, 0xa>(x);  // row_bcast:15 -> rows 1,3
    x = dppadd<0x143, 0xc>(x);  // row_bcast:31 -> rows 2,3
    return x;                    // lane 63 holds the full sum
}
__device__ __forceinline__ float wshr1(float x) {
    return __int_as_float(__builtin_amdgcn_update_dpp(
        0, __float_as_int(x), 0x138, 0xf, 0xf, true));
}
template <int CTRL>
__device__ __forceinline__ float dppmax(float x) {
    return fmaxf(x, __int_as_float(__builtin_amdgcn_update_dpp(
        0, __float_as_int(x), CTRL, 0xf, 0xf, false)));
}
__device__ __forceinline__ float wave_max64(float x) {
    x = dppmax<0x111>(x);
    x = dppmax<0x112>(x);
    x = dppmax<0x114>(x);
    x = dppmax<0x118>(x);
    x = dppmax<0x142>(x);
    x = dppmax<0x143>(x);
    return __int_as_float(__builtin_amdgcn_readlane(__float_as_int(x), 63));
}

// ---------------------------------------------------------------------------
// Kernel 1 (R18, unchanged): block = (b, pair of t's); exp(dec) inline.
// Diagonal-major log2-domain outputs:
//   BLD[b][t+u][u]  (stride 65) = (enc[0]+dec[u][0])*log2e     - lse2
//   EMD[b][t+u][u]  (stride 64) = (enc[tgt]+dec[u][tgt])*log2e - lse2
// Block 0 zeroes the output scalar.
// ---------------------------------------------------------------------------
__global__ __launch_bounds__(256) void k_logprobs(
    const float* __restrict__ enc, const float* __restrict__ dec,
    const int* __restrict__ targets,
    float* __restrict__ BLD, float* __restrict__ EMD,
    float* __restrict__ out)
{
    const int blk  = blockIdx.x;           // 0 .. 1023
    const int b    = blk % B_;             // XCD affinity with k_alpha
    const int tg   = blk / B_;
    const int t0   = tg * NT_;
    const int wave = threadIdx.x >> 6;
    const int lane = threadIdx.x & 63;

    if (blk == 0 && threadIdx.x == 0) out[0] = 0.0f;

    float4 xe0[NT_], xe1[NT_];
    float  er0[NT_];
    #pragma unroll
    for (int j = 0; j < NT_; ++j) {
        const float* erow = enc + (size_t)(b * T_ + t0 + j) * V_;
        float4 e0 = *(const float4*)(erow + lane * 4);
        float4 e1 = *(const float4*)(erow + 256 + lane * 4);
        xe0[j].x = __expf(e0.x); xe0[j].y = __expf(e0.y);
        xe0[j].z = __expf(e0.z); xe0[j].w = __expf(e0.w);
        xe1[j].x = __expf(e1.x); xe1[j].y = __expf(e1.y);
        xe1[j].z = __expf(e1.z); xe1[j].w = __expf(e1.w);
        er0[j] = erow[0];
    }

    for (int u = wave; u <= U_; u += 4) {
        const float* drow = dec + (size_t)(b * U1_ + u) * V_;
        float4 d0 = *(const float4*)(drow + lane * 4);
        float4 d1 = *(const float4*)(drow + 256 + lane * 4);
        d0.x = __expf(d0.x); d0.y = __expf(d0.y);
        d0.z = __expf(d0.z); d0.w = __expf(d0.w);
        d1.x = __expf(d1.x); d1.y = __expf(d1.y);
        d1.z = __expf(d1.z); d1.w = __expf(d1.w);

        float s[NT_];
        #pragma unroll
        for (int j = 0; j < NT_; ++j) {
            float sA = xe0[j].x * d0.x;
            float sB = xe1[j].x * d1.x;
            sA = fmaf(xe0[j].y, d0.y, sA);  sB = fmaf(xe1[j].y, d1.y, sB);
            sA = fmaf(xe0[j].z, d0.z, sA);  sB = fmaf(xe1[j].z, d1.z, sB);
            sA = fmaf(xe0[j].w, d0.w, sA);  sB = fmaf(xe1[j].w, d1.w, sB);
            s[j] = sA + sB;
        }

        #pragma unroll
        for (int j = 0; j < NT_; ++j)
            s[j] = wave_sum64(s[j]);

        if (lane == 63) {
            const float d_blank = drow[0];
            int   tgt = 0;
            float d_tgt = 0.0f;
            if (u < U_) { tgt = targets[b * U_ + u]; d_tgt = drow[tgt]; }
            #pragma unroll
            for (int j = 0; j < NT_; ++j) {
                const int t  = t0 + j;
                const int dg = t + u;
                const float lse2 = log2f(s[j]);
                BLD[((size_t)b * NDIAGP_ + dg) * U1_ + u] =
                    (er0[j] + d_blank) * LOG2E_ - lse2;
                if (u < U_) {
                    const float* er = enc + (size_t)(b * T_ + t) * V_;
                    EMD[((size_t)b * NDIAGP_ + dg) * U_ + u] =
                        (er[tgt] + d_tgt) * LOG2E_ - lse2;
                }
            }
        }
    }
}

// ---------------------------------------------------------------------------
// Kernel 2: alpha recursion, 2-phase.
// Phase 1: all 8 waves convert their 40 rows (reg-batched loads -> exp2 ->
//          bf16x2 pack -> one ds_write_b32). Whole PV table = 80 KB LDS.
// Phase 2: ONE barrier, then wave 0 runs all 320 diagonals from LDS
//          (1 ds_read_b32 per diagonal; renorm every 8; R18 capture).
// Row semantics (vs R18 chunk forms): refcol = row<256 ? 0 : row-255;
// t==0 patch: row<64 && lane==row; dead lanes: row>=256 && lane<=row-256.
// ---------------------------------------------------------------------------
#define LOADG(PW, PCQ, g_) do {                                                 \
    _Pragma("unroll")                                                           \
    for (int j = 0; j < 8; ++j)                                                 \
        PW[j] = sPV[(8 * (g_) + j) * 64 + lane];                                \
    PCQ[0] = pc4[2 * (g_)];                                                     \
    PCQ[1] = pc4[2 * (g_) + 1];                                                 \
} while (0)

#define PCSEL(PCQ, j_) ((j_) < 4 ? ((j_) == 0 ? PCQ[0].x : (j_) == 1 ? PCQ[0].y \
                                  : (j_) == 2 ? PCQ[0].z : PCQ[0].w)            \
                                 : ((j_) == 4 ? PCQ[1].x : (j_) == 5 ? PCQ[1].y \
                                  : (j_) == 6 ? PCQ[1].z : PCQ[1].w))

#define COMPG(PW, PCQ, g_) do {                                                 \
    _Pragma("unroll")                                                           \
    for (int j = 0; j < 8; ++j) {                                               \
        const int d = 8 * (g_) + j + 1;                                         \
        const unsigned int w = PW[j];                                           \
        const float pbv = __uint_as_float(w & 0xffff0000u);                     \
        const float pev = __uint_as_float(w << 16);                             \
        const float pcj = PCSEL(PCQ, j);                                        \
        float sr = wshr1(r);                                                    \
        sr = lane0 ? r0 : sr;                                                   \
        r = fmaf(sr, pev, r * pbv);                                             \
        const bool cap = (d == cap_d);                                          \
        savedV = cap ? (tlpos ? r : r0) : savedV;                               \
        savedC = cap ? (tlpos ? Rc + pcj : Rc) : savedC;                        \
        Rc += pcj;                                                              \
    }                                                                           \
    {   /* renormalize by exact 2^-e (branchless) */                            \
        float m = wave_max64(r);                                                \
        int mb = __float_as_int(m);                                             \
        int e = (mb >> 23) - 127;                                               \
        e = (mb >= 0x00800000) ? e : 0;                                         \
        float sc = __int_as_float((127 - e) << 23);                             \
        r *= sc;  r0 *= sc;  Rc += (float)e;                                    \
    }                                                                           \
} while (0)

__global__ __launch_bounds__(512) void k_alpha(
    const float* __restrict__ BLD, const float* __restrict__ EMD,
    const int* __restrict__ il_, const int* __restrict__ tl_,
    float* __restrict__ out)
{
    __shared__ __align__(16) unsigned int sPV[ND_ * 64];  // 80 KB bf16x2
    __shared__ __align__(16) float sPC[ND_];              // 1.25 KB refs

    const int b    = blockIdx.x;
    const int wave = threadIdx.x >> 6;
    const int lane = threadIdx.x & 63;
    const int il   = il_[b];
    const int tl   = tl_[b];
    const int dstar = il - 1 + tl;
    const float* BLb = BLD + (size_t)b * NDIAGP_ * U1_;
    const float* EMb = EMD + (size_t)b * NDIAGP_ * U_;

    // ---------------- phase 1: convert (all waves, 40 rows each) -----------
    for (int kb = 0; kb < 40; kb += 8) {
        float bl[8], em[8], pcv[8];
        #pragma unroll
        for (int j = 0; j < 8; ++j) {
            const int row = wave + 8 * (kb + j);
            const int rc  = row < 256 ? 0 : row - 255;
            bl[j]  = BLb[(size_t)row * U1_ + lane + 1];
            em[j]  = EMb[(size_t)row * U_ + lane];
            pcv[j] = BLb[(size_t)row * U1_ + rc];
        }
        #pragma unroll
        for (int j = 0; j < 8; ++j) {
            const int row = wave + 8 * (kb + j);
            float vb = fminf(bl[j] - pcv[j], 126.0f);
            float ve = fminf(em[j] - pcv[j], 126.0f);
            if (row < 64 && lane == row) vb = -200.0f;          // t==0 patch
            if (row >= 256 && lane <= row - 256) { vb = -200.0f; ve = -200.0f; }
            const unsigned int ub = __float_as_uint(EXP2(vb)) + 0x8000u;
            const unsigned int ue = __float_as_uint(EXP2(ve)) + 0x8000u;
            sPV[row * 64 + lane] = (ub & 0xffff0000u) | (ue >> 16);
            if (lane == 0) sPC[row] = pcv[j];
        }
    }
    __syncthreads();
    if (wave != 0) return;

    // ---------------- phase 2: serial chain (wave 0 only) ------------------
    const bool lane0 = (lane == 0);
    const bool tlpos = (tl > 0);
    const int  cap_d = tlpos ? dstar : il;

    float r  = 0.0f;   // 2^(alpha[u=lane+1] - R); 0 = not-yet-reachable
    float r0 = 1.0f;   // u=0 column (renorm-scaled only)
    float Rc = 0.0f;   // log2 reference prefix
    float savedV = 1.0f, savedC = 0.0f;

    const float4* pc4 = (const float4*)sPC;
    unsigned int pwA[8], pwB[8];
    float4 pcA[2], pcB[2];

    LOADG(pwA, pcA, 0);
    for (int g = 0; g < 40; g += 2) {
        LOADG(pwB, pcB, g + 1);
        COMPG(pwA, pcA, g);
        if (g + 2 < 40) LOADG(pwA, pcA, g + 2);
        COMPG(pwB, pcB, g + 1);
    }

    {
        const int sl = tlpos ? (tl - 1) : 0;
        float sv = __int_as_float(
            __builtin_amdgcn_readlane(__float_as_int(savedV), sl));
        float sc = __int_as_float(
            __builtin_amdgcn_readlane(__float_as_int(savedC), 0));
        if (lane == 0) {
            const float fblank = BLb[(size_t)dstar * U1_ + tl];
            atomicAdd(out, -(sc + log2f(sv) + fblank) * (LN2_ / B_));
        }
    }
}

extern "C" void kernel_launch(void* const* d_in, const int* in_sizes, int n_in,
                              void* d_out, int out_size, void* d_ws, size_t ws_size,
                              hipStream_t stream)
{
    const float* enc     = (const float*)d_in[0];
    const float* dec     = (const float*)d_in[1];
    const int*   targets = (const int*)d_in[2];
    const int*   il      = (const int*)d_in[3];
    const int*   tl      = (const int*)d_in[4];
    float*       out     = (float*)d_out;

    float* BLD = (float*)d_ws;                            // B*NDIAGP*U1
    float* EMD = BLD + (size_t)B_ * NDIAGP_ * U1_;        // B*NDIAGP*U_

    k_logprobs<<<B_ * T_ / NT_, 256, 0, stream>>>(enc, dec, targets, BLD, EMD, out);
    k_alpha<<<B_, 512, 0, stream>>>(BLD, EMD, il, tl, out);
}